// Round 2
// baseline (449.350 us; speedup 1.0000x reference)
//
#include <hip/hip_runtime.h>
#include <math.h>

__device__ __forceinline__ float gelu_f(float x) {
    return 0.5f * x * (1.0f + erff(x * 0.7071067811865476f));
}

// ---------------------------------------------------------------------------
// K0: precompute cc[k] = sum_c cb[k][c]^2   (512 codes, 32 ch)
// ---------------------------------------------------------------------------
__global__ __launch_bounds__(256) void k_prep(const float* __restrict__ cb,
                                              float* __restrict__ ccp) {
    const int k = blockIdx.x * 256 + threadIdx.x;
    if (k < 512) {
        const float* row = cb + k * 32;
        float s = 0.f;
#pragma unroll
        for (int c = 0; c < 32; ++c) s += row[c] * row[c];
        ccp[k] = s;
    }
}

// ---------------------------------------------------------------------------
// K1: conv1 (1->16, 3x3, SAME) + maxpool2 + gelu
// x[128,1,128,128] -> h1[128,16,64,64]
// ---------------------------------------------------------------------------
__global__ __launch_bounds__(256) void k_conv1(const float* __restrict__ x,
                                               const float* __restrict__ w1,
                                               const float* __restrict__ b1,
                                               float* __restrict__ h1) {
    __shared__ float xs[34][35];
    __shared__ float wS[16][9];
    __shared__ float bS[16];
    const int blk = blockIdx.x;
    const int b = blk >> 4;
    const int tile = blk & 15;
    const int ti = (tile >> 2) << 4, tj = (tile & 3) << 4;
    const int t = threadIdx.x;
    if (t < 144) wS[t / 9][t % 9] = w1[t];
    if (t < 16) bS[t] = b1[t];
    const float* xb = x + b * 16384;
    for (int i = t; i < 34 * 34; i += 256) {
        const int r = i / 34, c = i % 34;
        const int gr = 2 * ti - 1 + r, gc = 2 * tj - 1 + c;
        xs[r][c] = ((unsigned)gr < 128u && (unsigned)gc < 128u) ? xb[gr * 128 + gc] : 0.f;
    }
    __syncthreads();
    const int jj = t & 15, ii = t >> 4;
    float pat[4][4];
#pragma unroll
    for (int r = 0; r < 4; r++)
#pragma unroll
        for (int c = 0; c < 4; c++) pat[r][c] = xs[2 * ii + r][2 * jj + c];
    const int obase = b * 65536 + (ti + ii) * 64 + (tj + jj);
#pragma unroll
    for (int co = 0; co < 16; co++) {
        float w[9];
#pragma unroll
        for (int k = 0; k < 9; k++) w[k] = wS[co][k];
        float s00 = 0.f, s01 = 0.f, s10 = 0.f, s11 = 0.f;
#pragma unroll
        for (int ty = 0; ty < 3; ty++)
#pragma unroll
            for (int tx = 0; tx < 3; tx++) {
                const float wv = w[ty * 3 + tx];
                s00 += wv * pat[ty][tx];
                s01 += wv * pat[ty][tx + 1];
                s10 += wv * pat[ty + 1][tx];
                s11 += wv * pat[ty + 1][tx + 1];
            }
        const float m = fmaxf(fmaxf(s00, s01), fmaxf(s10, s11)) + bS[co];
        h1[obase + co * 4096] = gelu_f(m);
    }
}

// ---------------------------------------------------------------------------
// K2: conv2 (16->32, 3x3, SAME) + maxpool2 (no activation)
// h1[128,16,64,64] -> h[128,32,32,32]
// ---------------------------------------------------------------------------
__global__ __launch_bounds__(256) void k_conv2(const float* __restrict__ h1,
                                               const float* __restrict__ w2,
                                               const float* __restrict__ b2,
                                               float* __restrict__ h) {
    __shared__ float hs[16][18][19];
    __shared__ float wS[32][145];
    __shared__ float bS[32];
    const int blk = blockIdx.x;
    const int b = blk >> 4;
    const int tile = blk & 15;
    const int ti = (tile >> 2) << 3, tj = (tile & 3) << 3;
    const int t = threadIdx.x;
    for (int i = t; i < 32 * 144; i += 256) wS[i / 144][i % 144] = w2[i];
    if (t < 32) bS[t] = b2[t];
    const float* h1b = h1 + b * 65536;
    for (int i = t; i < 16 * 324; i += 256) {
        const int ci = i / 324, rc = i % 324, r = rc / 18, c = rc % 18;
        const int gr = 2 * ti - 1 + r, gc = 2 * tj - 1 + c;
        hs[ci][r][c] = ((unsigned)gr < 64u && (unsigned)gc < 64u) ? h1b[ci * 4096 + gr * 64 + gc] : 0.f;
    }
    __syncthreads();
    const int co = t >> 3, irow = t & 7;
    float acc0[8], acc1[8], acc2[8], acc3[8];
#pragma unroll
    for (int j = 0; j < 8; j++) { acc0[j] = 0.f; acc1[j] = 0.f; acc2[j] = 0.f; acc3[j] = 0.f; }
#pragma unroll 1
    for (int ci = 0; ci < 16; ci++) {
        float w[9];
#pragma unroll
        for (int k = 0; k < 9; k++) w[k] = wS[co][ci * 9 + k];
        float pat[4][4];
#pragma unroll
        for (int r = 0; r < 4; r++)
#pragma unroll
            for (int c = 0; c < 4; c++) pat[r][c] = hs[ci][2 * irow + r][c];
#pragma unroll
        for (int j = 0; j < 8; j++) {
#pragma unroll
            for (int ty = 0; ty < 3; ty++)
#pragma unroll
                for (int tx = 0; tx < 3; tx++) {
                    const float wv = w[ty * 3 + tx];
                    acc0[j] += wv * pat[ty][tx];
                    acc1[j] += wv * pat[ty][tx + 1];
                    acc2[j] += wv * pat[ty + 1][tx];
                    acc3[j] += wv * pat[ty + 1][tx + 1];
                }
            if (j < 7) {
#pragma unroll
                for (int r = 0; r < 4; r++) {
                    pat[r][0] = pat[r][2]; pat[r][1] = pat[r][3];
                    pat[r][2] = hs[ci][2 * irow + r][2 * j + 4];
                    pat[r][3] = hs[ci][2 * irow + r][2 * j + 5];
                }
            }
        }
    }
    float* hb = h + (b * 32 + co) * 1024 + (ti + irow) * 32 + tj;
#pragma unroll
    for (int j = 0; j < 8; j++) {
        hb[j] = fmaxf(fmaxf(acc0[j], acc1[j]), fmaxf(acc2[j], acc3[j])) + bS[co];
    }
}

// ---------------------------------------------------------------------------
// K3: VectorQuantize, scalar-broadcast codebook version.
// Each lane owns one n: z[32] in VGPRs (coalesced loads), codebook row k is
// wave-uniform -> s_load broadcast. No LDS staging, no shuffle argmin.
// Ascending k + strict < keeps the first minimum (matches jnp.argmin).
// d2 expression kept byte-identical to the R0-passing kernel:
//   d2 = (zz - 2.f*dot) + cc[k]
// ---------------------------------------------------------------------------
__global__ __launch_bounds__(256) void k_vq(const float* __restrict__ h,
                                            const float* __restrict__ cb,
                                            const float* __restrict__ ccp,
                                            float* __restrict__ idx_out,
                                            float* __restrict__ partials) {
    const int t = threadIdx.x;
    const int n = blockIdx.x * 256 + t;          // flat n in [0, 131072)
    const int b = n >> 10, pos = n & 1023;
    const float* hb = h + b * 32768 + pos;
    float z[32];
    float zz = 0.f;
#pragma unroll
    for (int c = 0; c < 32; ++c) {
        z[c] = hb[c * 1024];
        zz += z[c] * z[c];
    }
    float bd = 3.4e38f;
    float bk = 0.f;
#pragma unroll 2
    for (int k = 0; k < 512; ++k) {
        const float* ck = cb + (k << 5);
        float dot = 0.f;
#pragma unroll
        for (int c = 0; c < 32; ++c) dot += z[c] * ck[c];
        const float d2 = (zz - 2.f * dot) + ccp[k];
        const float fk = (float)k;
        if (d2 < bd) { bd = d2; bk = fk; }
    }
    idx_out[n] = bk;
    __shared__ float red[256];
    red[t] = bd;
    __syncthreads();
    for (int off = 128; off > 0; off >>= 1) {
        if (t < off) red[t] += red[t + off];
        __syncthreads();
    }
    if (t == 0) partials[blockIdx.x] = red[0];
}

// ---------------------------------------------------------------------------
// K4: conv3 (32->16, 3x3, SAME) on nearest-2x-upsampled h, + gelu.
// h[128,32,32,32] -> g[128,16,64,64]
// ---------------------------------------------------------------------------
__global__ __launch_bounds__(256) void k_conv3(const float* __restrict__ h,
                                               const float* __restrict__ w3,
                                               const float* __restrict__ b3,
                                               float* __restrict__ g) {
    __shared__ float hS[32][10][34];
    __shared__ float wS[16][289];
    __shared__ float bS[16];
    const int blk = blockIdx.x;
    const int b = blk >> 2, strip = blk & 3;
    const int p0 = strip * 16, i0 = strip * 8;
    const int t = threadIdx.x;
    for (int i = t; i < 16 * 288; i += 256) wS[i / 288][i % 288] = w3[i];
    if (t < 16) bS[t] = b3[t];
    const float* hb = h + b * 32768;
    for (int i = t; i < 32 * 340; i += 256) {
        const int ci = i / 340, rc = i % 340, r = rc / 34, c = rc % 34;
        const int gr = i0 - 1 + r, gc = c - 1;
        hS[ci][r][c] = ((unsigned)gr < 32u && (unsigned)gc < 32u) ? hb[ci * 1024 + gr * 32 + gc] : 0.f;
    }
    __syncthreads();
    const int co = t & 15, rowid = t >> 4;
    const int p = p0 + rowid;
    const int pe = p & 1;
    const int iq = p >> 1;
    const int lrA = (pe ? iq : iq - 1) - (i0 - 1);
    float acc[64];
#pragma unroll
    for (int q = 0; q < 64; q++) acc[q] = 0.f;
#pragma unroll 1
    for (int ci = 0; ci < 32; ci++) {
        float w[9];
#pragma unroll
        for (int k = 0; k < 9; k++) w[k] = wS[co][ci * 9 + k];
        const float rA0 = pe ? (w[0] + w[3]) : w[0];
        const float rA1 = pe ? (w[1] + w[4]) : w[1];
        const float rA2 = pe ? (w[2] + w[5]) : w[2];
        const float rB0 = pe ? w[6] : (w[3] + w[6]);
        const float rB1 = pe ? w[7] : (w[4] + w[7]);
        const float rB2 = pe ? w[8] : (w[5] + w[8]);
        const float we_a0 = rA0, we_a1 = rA1 + rA2;
        const float we_b0 = rB0, we_b1 = rB1 + rB2;
        const float wo_a0 = rA0 + rA1, wo_a1 = rA2;
        const float wo_b0 = rB0 + rB1, wo_b1 = rB2;
        const float* hA = &hS[ci][lrA][0];
        const float* hB = &hS[ci][lrA + 1][0];
        float a0 = hA[0], a1 = hA[1];
        float c0 = hB[0], c1 = hB[1];
#pragma unroll
        for (int j = 0; j < 32; j++) {
            const float a2 = hA[j + 2];
            const float c2 = hB[j + 2];
            acc[2 * j]     += we_a0 * a0 + we_a1 * a1 + we_b0 * c0 + we_b1 * c1;
            acc[2 * j + 1] += wo_a0 * a1 + wo_a1 * a2 + wo_b0 * c1 + wo_b1 * c2;
            a0 = a1; a1 = a2; c0 = c1; c1 = c2;
        }
    }
    const float bias = bS[co];
    float4* g4 = (float4*)(g + (b * 16 + co) * 4096 + p * 64);
#pragma unroll
    for (int q4 = 0; q4 < 16; q4++) {
        float4 v;
        v.x = gelu_f(acc[4 * q4 + 0] + bias);
        v.y = gelu_f(acc[4 * q4 + 1] + bias);
        v.z = gelu_f(acc[4 * q4 + 2] + bias);
        v.w = gelu_f(acc[4 * q4 + 3] + bias);
        g4[q4] = v;
    }
}

// ---------------------------------------------------------------------------
// K5: conv4 (16->1, 3x3, SAME) on nearest-2x-upsampled g, + clip [-1,1].
// g[128,16,64,64] -> out[128,1,128,128]
// ---------------------------------------------------------------------------
__global__ __launch_bounds__(256) void k_conv4(const float* __restrict__ g,
                                               const float* __restrict__ w4,
                                               const float* __restrict__ b4,
                                               float* __restrict__ out) {
    __shared__ float gS[16][10][66];
    __shared__ float wS[16][9];
    const int blk = blockIdx.x;
    const int b = blk >> 3, strip = blk & 7;
    const int p0 = strip * 16, i0 = strip * 8;
    const int t = threadIdx.x;
    if (t < 144) wS[t / 9][t % 9] = w4[t];
    const float* gb = g + b * 65536;
    for (int i = t; i < 16 * 660; i += 256) {
        const int ci = i / 660, rc = i % 660, r = rc / 66, c = rc % 66;
        const int gr = i0 - 1 + r, gc = c - 1;
        gS[ci][r][c] = ((unsigned)gr < 64u && (unsigned)gc < 64u) ? gb[ci * 4096 + gr * 64 + gc] : 0.f;
    }
    __syncthreads();
    const int rowid = t >> 4, cg = t & 15;
    const int p = p0 + rowid;
    const int pe = p & 1;
    const int iq = p >> 1;
    const int lrA = (pe ? iq : iq - 1) - (i0 - 1);
    float acc[8];
#pragma unroll
    for (int q = 0; q < 8; q++) acc[q] = 0.f;
#pragma unroll 1
    for (int ci = 0; ci < 16; ci++) {
        float w[9];
#pragma unroll
        for (int k = 0; k < 9; k++) w[k] = wS[ci][k];
        const float rA0 = pe ? (w[0] + w[3]) : w[0];
        const float rA1 = pe ? (w[1] + w[4]) : w[1];
        const float rA2 = pe ? (w[2] + w[5]) : w[2];
        const float rB0 = pe ? w[6] : (w[3] + w[6]);
        const float rB1 = pe ? w[7] : (w[4] + w[7]);
        const float rB2 = pe ? w[8] : (w[5] + w[8]);
        const float we_a0 = rA0, we_a1 = rA1 + rA2;
        const float we_b0 = rB0, we_b1 = rB1 + rB2;
        const float wo_a0 = rA0 + rA1, wo_a1 = rA2;
        const float wo_b0 = rB0 + rB1, wo_b1 = rB2;
        const float* hA = &gS[ci][lrA][4 * cg];
        const float* hB = &gS[ci][lrA + 1][4 * cg];
        float a0 = hA[0], a1 = hA[1];
        float c0 = hB[0], c1 = hB[1];
#pragma unroll
        for (int j = 0; j < 4; j++) {
            const float a2 = hA[j + 2];
            const float c2 = hB[j + 2];
            acc[2 * j]     += we_a0 * a0 + we_a1 * a1 + we_b0 * c0 + we_b1 * c1;
            acc[2 * j + 1] += wo_a0 * a1 + wo_a1 * a2 + wo_b0 * c1 + wo_b1 * c2;
            a0 = a1; a1 = a2; c0 = c1; c1 = c2;
        }
    }
    const float bias = b4[0];
    float* ob = out + b * 16384 + p * 128 + 8 * cg;
#pragma unroll
    for (int q = 0; q < 8; q++) ob[q] = fminf(fmaxf(acc[q] + bias, -1.f), 1.f);
}

// ---------------------------------------------------------------------------
// K6: deterministic loss reduction: mean over B*N*C = 4194304 elements
// ---------------------------------------------------------------------------
__global__ __launch_bounds__(256) void k_reduce(const float* __restrict__ partials,
                                                float* __restrict__ loss) {
    __shared__ float red[256];
    const int t = threadIdx.x;
    float s = 0.f;
    for (int i = t; i < 512; i += 256) s += partials[i];
    red[t] = s;
    __syncthreads();
    for (int off = 128; off > 0; off >>= 1) {
        if (t < off) red[t] += red[t + off];
        __syncthreads();
    }
    if (t == 0) loss[0] = red[0] * (1.0f / 4194304.0f);
}

extern "C" void kernel_launch(void* const* d_in, const int* in_sizes, int n_in,
                              void* d_out, int out_size, void* d_ws, size_t ws_size,
                              hipStream_t stream) {
    const float* x  = (const float*)d_in[0];
    const float* w1 = (const float*)d_in[1];
    const float* b1 = (const float*)d_in[2];
    const float* w2 = (const float*)d_in[3];
    const float* b2 = (const float*)d_in[4];
    const float* cb = (const float*)d_in[5];
    const float* w3 = (const float*)d_in[6];
    const float* b3 = (const float*)d_in[7];
    const float* w4 = (const float*)d_in[8];
    const float* b4 = (const float*)d_in[9];

    float* ws = (float*)d_ws;
    float* h1 = ws;                  // 8388608 floats [128,16,64,64]; reused as g
    float* h  = ws + 8388608;        // 4194304 floats [128,32,32,32]
    float* g  = h1;                  // alias: h1 dead after k_conv2
    float* ccp = ws + 12582912;      // 512 floats
    float* pa  = ws + 12583424;      // 512 floats (per-block loss partials)
    float* outp = (float*)d_out;     // [out 2097152][idx 131072][loss 1]

    k_prep<<<2, 256, 0, stream>>>(cb, ccp);
    k_conv1<<<2048, 256, 0, stream>>>(x, w1, b1, h1);
    k_conv2<<<2048, 256, 0, stream>>>(h1, w2, b2, h);
    k_vq<<<512, 256, 0, stream>>>(h, cb, ccp, outp + 2097152, pa);
    k_conv3<<<512, 256, 0, stream>>>(h, w3, b3, g);
    k_conv4<<<1024, 256, 0, stream>>>(g, w4, b4, outp);
    k_reduce<<<1, 256, 0, stream>>>(pa, outp + 2228224);
}

// Round 3
// 292.968 us; speedup vs baseline: 1.5338x; 1.5338x over previous
//
#include <hip/hip_runtime.h>
#include <math.h>

__device__ __forceinline__ float gelu_f(float x) {
    return 0.5f * x * (1.0f + erff(x * 0.7071067811865476f));
}

// ---------------------------------------------------------------------------
// K0: precompute cc[k] = sum_c cb[k][c]^2   (512 codes, 32 ch)
// ---------------------------------------------------------------------------
__global__ __launch_bounds__(256) void k_prep(const float* __restrict__ cb,
                                              float* __restrict__ ccp) {
    const int k = blockIdx.x * 256 + threadIdx.x;
    if (k < 512) {
        const float* row = cb + k * 32;
        float s = 0.f;
#pragma unroll
        for (int c = 0; c < 32; ++c) s += row[c] * row[c];
        ccp[k] = s;
    }
}

// ---------------------------------------------------------------------------
// K1: conv1 (1->16, 3x3, SAME) + maxpool2 + gelu
// x[128,1,128,128] -> h1[128,16,64,64]
// ---------------------------------------------------------------------------
__global__ __launch_bounds__(256) void k_conv1(const float* __restrict__ x,
                                               const float* __restrict__ w1,
                                               const float* __restrict__ b1,
                                               float* __restrict__ h1) {
    __shared__ float xs[34][35];
    __shared__ float wS[16][9];
    __shared__ float bS[16];
    const int blk = blockIdx.x;
    const int b = blk >> 4;
    const int tile = blk & 15;
    const int ti = (tile >> 2) << 4, tj = (tile & 3) << 4;
    const int t = threadIdx.x;
    if (t < 144) wS[t / 9][t % 9] = w1[t];
    if (t < 16) bS[t] = b1[t];
    const float* xb = x + b * 16384;
    for (int i = t; i < 34 * 34; i += 256) {
        const int r = i / 34, c = i % 34;
        const int gr = 2 * ti - 1 + r, gc = 2 * tj - 1 + c;
        xs[r][c] = ((unsigned)gr < 128u && (unsigned)gc < 128u) ? xb[gr * 128 + gc] : 0.f;
    }
    __syncthreads();
    const int jj = t & 15, ii = t >> 4;
    float pat[4][4];
#pragma unroll
    for (int r = 0; r < 4; r++)
#pragma unroll
        for (int c = 0; c < 4; c++) pat[r][c] = xs[2 * ii + r][2 * jj + c];
    const int obase = b * 65536 + (ti + ii) * 64 + (tj + jj);
#pragma unroll
    for (int co = 0; co < 16; co++) {
        float w[9];
#pragma unroll
        for (int k = 0; k < 9; k++) w[k] = wS[co][k];
        float s00 = 0.f, s01 = 0.f, s10 = 0.f, s11 = 0.f;
#pragma unroll
        for (int ty = 0; ty < 3; ty++)
#pragma unroll
            for (int tx = 0; tx < 3; tx++) {
                const float wv = w[ty * 3 + tx];
                s00 += wv * pat[ty][tx];
                s01 += wv * pat[ty][tx + 1];
                s10 += wv * pat[ty + 1][tx];
                s11 += wv * pat[ty + 1][tx + 1];
            }
        const float m = fmaxf(fmaxf(s00, s01), fmaxf(s10, s11)) + bS[co];
        h1[obase + co * 4096] = gelu_f(m);
    }
}

// ---------------------------------------------------------------------------
// K2: conv2 (16->32, 3x3, SAME) + maxpool2 (no activation)
// h1[128,16,64,64] -> h[128,32,32,32]
// ---------------------------------------------------------------------------
__global__ __launch_bounds__(256) void k_conv2(const float* __restrict__ h1,
                                               const float* __restrict__ w2,
                                               const float* __restrict__ b2,
                                               float* __restrict__ h) {
    __shared__ float hs[16][18][19];
    __shared__ float wS[32][145];
    __shared__ float bS[32];
    const int blk = blockIdx.x;
    const int b = blk >> 4;
    const int tile = blk & 15;
    const int ti = (tile >> 2) << 3, tj = (tile & 3) << 3;
    const int t = threadIdx.x;
    for (int i = t; i < 32 * 144; i += 256) wS[i / 144][i % 144] = w2[i];
    if (t < 32) bS[t] = b2[t];
    const float* h1b = h1 + b * 65536;
    for (int i = t; i < 16 * 324; i += 256) {
        const int ci = i / 324, rc = i % 324, r = rc / 18, c = rc % 18;
        const int gr = 2 * ti - 1 + r, gc = 2 * tj - 1 + c;
        hs[ci][r][c] = ((unsigned)gr < 64u && (unsigned)gc < 64u) ? h1b[ci * 4096 + gr * 64 + gc] : 0.f;
    }
    __syncthreads();
    const int co = t >> 3, irow = t & 7;
    float acc0[8], acc1[8], acc2[8], acc3[8];
#pragma unroll
    for (int j = 0; j < 8; j++) { acc0[j] = 0.f; acc1[j] = 0.f; acc2[j] = 0.f; acc3[j] = 0.f; }
#pragma unroll 1
    for (int ci = 0; ci < 16; ci++) {
        float w[9];
#pragma unroll
        for (int k = 0; k < 9; k++) w[k] = wS[co][ci * 9 + k];
        float pat[4][4];
#pragma unroll
        for (int r = 0; r < 4; r++)
#pragma unroll
            for (int c = 0; c < 4; c++) pat[r][c] = hs[ci][2 * irow + r][c];
#pragma unroll
        for (int j = 0; j < 8; j++) {
#pragma unroll
            for (int ty = 0; ty < 3; ty++)
#pragma unroll
                for (int tx = 0; tx < 3; tx++) {
                    const float wv = w[ty * 3 + tx];
                    acc0[j] += wv * pat[ty][tx];
                    acc1[j] += wv * pat[ty][tx + 1];
                    acc2[j] += wv * pat[ty + 1][tx];
                    acc3[j] += wv * pat[ty + 1][tx + 1];
                }
            if (j < 7) {
#pragma unroll
                for (int r = 0; r < 4; r++) {
                    pat[r][0] = pat[r][2]; pat[r][1] = pat[r][3];
                    pat[r][2] = hs[ci][2 * irow + r][2 * j + 4];
                    pat[r][3] = hs[ci][2 * irow + r][2 * j + 5];
                }
            }
        }
    }
    float* hb = h + (b * 32 + co) * 1024 + (ti + irow) * 32 + tj;
#pragma unroll
    for (int j = 0; j < 8; j++) {
        hb[j] = fmaxf(fmaxf(acc0[j], acc1[j]), fmaxf(acc2[j], acc3[j])) + bS[co];
    }
}

// ---------------------------------------------------------------------------
// K3a: VQ partial argmin. Grid 2048 = 512 n-chunks * 4 k-splits (128 codes ea).
// Each lane owns one n; z[32] in VGPRs (coalesced); codebook rows wave-uniform
// (scalar loads). k unrolled by 2, 2 partial accumulators per dot -> 4
// independent FMA chains. Ascending k + strict < == first-min (jnp.argmin).
// d2 formula identical to passing rounds: (zz - 2.f*dot) + cc[k].
// part[ks][n] = (bd, bk) coalesced.
// ---------------------------------------------------------------------------
__global__ __launch_bounds__(256) void k_vq_part(const float* __restrict__ h,
                                                 const float* __restrict__ cb,
                                                 const float* __restrict__ ccp,
                                                 float2* __restrict__ part) {
    const int blk = blockIdx.x;
    const int nchunk = blk >> 2, ks = blk & 3;
    const int t = threadIdx.x;
    const int n = nchunk * 256 + t;
    const int b = n >> 10, pos = n & 1023;
    const float* hb = h + b * 32768 + pos;
    float z[32];
    float zz = 0.f;
#pragma unroll
    for (int c = 0; c < 32; ++c) {
        z[c] = hb[c * 1024];
        zz += z[c] * z[c];
    }
    const int kbase = ks << 7;
    const float* cbb = cb + (kbase << 5);
    const float* ccb = ccp + kbase;
    float bd = 3.4e38f;
    int bk = 0;
#pragma unroll 1
    for (int kk = 0; kk < 128; kk += 2) {
        const float* r0 = cbb + (kk << 5);
        const float* r1 = r0 + 32;
        float d0a = 0.f, d0b = 0.f, d1a = 0.f, d1b = 0.f;
#pragma unroll
        for (int c = 0; c < 32; c += 2) {
            d0a += z[c] * r0[c];
            d0b += z[c + 1] * r0[c + 1];
            d1a += z[c] * r1[c];
            d1b += z[c + 1] * r1[c + 1];
        }
        const float dot0 = d0a + d0b;
        const float dot1 = d1a + d1b;
        const float e0 = (zz - 2.f * dot0) + ccb[kk];
        const float e1 = (zz - 2.f * dot1) + ccb[kk + 1];
        if (e0 < bd) { bd = e0; bk = kbase + kk; }
        if (e1 < bd) { bd = e1; bk = kbase + kk + 1; }
    }
    part[ks * 131072 + n] = make_float2(bd, (float)bk);
}

// ---------------------------------------------------------------------------
// K3b: combine 4 k-split partials per n. Splits visited in ascending-k order
// with strict < -> lower k wins ties, matching jnp.argmin. Also reduces the
// per-block sum of min-distances for the commit loss.
// ---------------------------------------------------------------------------
__global__ __launch_bounds__(256) void k_vq_comb(const float2* __restrict__ part,
                                                 float* __restrict__ idx_out,
                                                 float* __restrict__ partials) {
    const int t = threadIdx.x;
    const int n = blockIdx.x * 256 + t;
    float2 p0 = part[n];
    float2 p1 = part[131072 + n];
    float2 p2 = part[262144 + n];
    float2 p3 = part[393216 + n];
    float bd = p0.x;
    float bk = p0.y;
    if (p1.x < bd) { bd = p1.x; bk = p1.y; }
    if (p2.x < bd) { bd = p2.x; bk = p2.y; }
    if (p3.x < bd) { bd = p3.x; bk = p3.y; }
    idx_out[n] = bk;
    __shared__ float red[256];
    red[t] = bd;
    __syncthreads();
    for (int off = 128; off > 0; off >>= 1) {
        if (t < off) red[t] += red[t + off];
        __syncthreads();
    }
    if (t == 0) partials[blockIdx.x] = red[0];
}

// ---------------------------------------------------------------------------
// K4: conv3 (32->16, 3x3, SAME) on nearest-2x-upsampled h, + gelu.
// h[128,32,32,32] -> g[128,16,64,64]
// ---------------------------------------------------------------------------
__global__ __launch_bounds__(256) void k_conv3(const float* __restrict__ h,
                                               const float* __restrict__ w3,
                                               const float* __restrict__ b3,
                                               float* __restrict__ g) {
    __shared__ float hS[32][10][34];
    __shared__ float wS[16][289];
    __shared__ float bS[16];
    const int blk = blockIdx.x;
    const int b = blk >> 2, strip = blk & 3;
    const int p0 = strip * 16, i0 = strip * 8;
    const int t = threadIdx.x;
    for (int i = t; i < 16 * 288; i += 256) wS[i / 288][i % 288] = w3[i];
    if (t < 16) bS[t] = b3[t];
    const float* hb = h + b * 32768;
    for (int i = t; i < 32 * 340; i += 256) {
        const int ci = i / 340, rc = i % 340, r = rc / 34, c = rc % 34;
        const int gr = i0 - 1 + r, gc = c - 1;
        hS[ci][r][c] = ((unsigned)gr < 32u && (unsigned)gc < 32u) ? hb[ci * 1024 + gr * 32 + gc] : 0.f;
    }
    __syncthreads();
    const int co = t & 15, rowid = t >> 4;
    const int p = p0 + rowid;
    const int pe = p & 1;
    const int iq = p >> 1;
    const int lrA = (pe ? iq : iq - 1) - (i0 - 1);
    float acc[64];
#pragma unroll
    for (int q = 0; q < 64; q++) acc[q] = 0.f;
#pragma unroll 1
    for (int ci = 0; ci < 32; ci++) {
        float w[9];
#pragma unroll
        for (int k = 0; k < 9; k++) w[k] = wS[co][ci * 9 + k];
        const float rA0 = pe ? (w[0] + w[3]) : w[0];
        const float rA1 = pe ? (w[1] + w[4]) : w[1];
        const float rA2 = pe ? (w[2] + w[5]) : w[2];
        const float rB0 = pe ? w[6] : (w[3] + w[6]);
        const float rB1 = pe ? w[7] : (w[4] + w[7]);
        const float rB2 = pe ? w[8] : (w[5] + w[8]);
        const float we_a0 = rA0, we_a1 = rA1 + rA2;
        const float we_b0 = rB0, we_b1 = rB1 + rB2;
        const float wo_a0 = rA0 + rA1, wo_a1 = rA2;
        const float wo_b0 = rB0 + rB1, wo_b1 = rB2;
        const float* hA = &hS[ci][lrA][0];
        const float* hB = &hS[ci][lrA + 1][0];
        float a0 = hA[0], a1 = hA[1];
        float c0 = hB[0], c1 = hB[1];
#pragma unroll
        for (int j = 0; j < 32; j++) {
            const float a2 = hA[j + 2];
            const float c2 = hB[j + 2];
            acc[2 * j]     += we_a0 * a0 + we_a1 * a1 + we_b0 * c0 + we_b1 * c1;
            acc[2 * j + 1] += wo_a0 * a1 + wo_a1 * a2 + wo_b0 * c1 + wo_b1 * c2;
            a0 = a1; a1 = a2; c0 = c1; c1 = c2;
        }
    }
    const float bias = bS[co];
    float4* g4 = (float4*)(g + (b * 16 + co) * 4096 + p * 64);
#pragma unroll
    for (int q4 = 0; q4 < 16; q4++) {
        float4 v;
        v.x = gelu_f(acc[4 * q4 + 0] + bias);
        v.y = gelu_f(acc[4 * q4 + 1] + bias);
        v.z = gelu_f(acc[4 * q4 + 2] + bias);
        v.w = gelu_f(acc[4 * q4 + 3] + bias);
        g4[q4] = v;
    }
}

// ---------------------------------------------------------------------------
// K5: conv4 (16->1, 3x3, SAME) on nearest-2x-upsampled g, + clip [-1,1].
// g[128,16,64,64] -> out[128,1,128,128]
// ---------------------------------------------------------------------------
__global__ __launch_bounds__(256) void k_conv4(const float* __restrict__ g,
                                               const float* __restrict__ w4,
                                               const float* __restrict__ b4,
                                               float* __restrict__ out) {
    __shared__ float gS[16][10][66];
    __shared__ float wS[16][9];
    const int blk = blockIdx.x;
    const int b = blk >> 3, strip = blk & 7;
    const int p0 = strip * 16, i0 = strip * 8;
    const int t = threadIdx.x;
    if (t < 144) wS[t / 9][t % 9] = w4[t];
    const float* gb = g + b * 65536;
    for (int i = t; i < 16 * 660; i += 256) {
        const int ci = i / 660, rc = i % 660, r = rc / 66, c = rc % 66;
        const int gr = i0 - 1 + r, gc = c - 1;
        gS[ci][r][c] = ((unsigned)gr < 64u && (unsigned)gc < 64u) ? gb[ci * 4096 + gr * 64 + gc] : 0.f;
    }
    __syncthreads();
    const int rowid = t >> 4, cg = t & 15;
    const int p = p0 + rowid;
    const int pe = p & 1;
    const int iq = p >> 1;
    const int lrA = (pe ? iq : iq - 1) - (i0 - 1);
    float acc[8];
#pragma unroll
    for (int q = 0; q < 8; q++) acc[q] = 0.f;
#pragma unroll 1
    for (int ci = 0; ci < 16; ci++) {
        float w[9];
#pragma unroll
        for (int k = 0; k < 9; k++) w[k] = wS[ci][k];
        const float rA0 = pe ? (w[0] + w[3]) : w[0];
        const float rA1 = pe ? (w[1] + w[4]) : w[1];
        const float rA2 = pe ? (w[2] + w[5]) : w[2];
        const float rB0 = pe ? w[6] : (w[3] + w[6]);
        const float rB1 = pe ? w[7] : (w[4] + w[7]);
        const float rB2 = pe ? w[8] : (w[5] + w[8]);
        const float we_a0 = rA0, we_a1 = rA1 + rA2;
        const float we_b0 = rB0, we_b1 = rB1 + rB2;
        const float wo_a0 = rA0 + rA1, wo_a1 = rA2;
        const float wo_b0 = rB0 + rB1, wo_b1 = rB2;
        const float* hA = &gS[ci][lrA][4 * cg];
        const float* hB = &gS[ci][lrA + 1][4 * cg];
        float a0 = hA[0], a1 = hA[1];
        float c0 = hB[0], c1 = hB[1];
#pragma unroll
        for (int j = 0; j < 4; j++) {
            const float a2 = hA[j + 2];
            const float c2 = hB[j + 2];
            acc[2 * j]     += we_a0 * a0 + we_a1 * a1 + we_b0 * c0 + we_b1 * c1;
            acc[2 * j + 1] += wo_a0 * a1 + wo_a1 * a2 + wo_b0 * c1 + wo_b1 * c2;
            a0 = a1; a1 = a2; c0 = c1; c1 = c2;
        }
    }
    const float bias = b4[0];
    float* ob = out + b * 16384 + p * 128 + 8 * cg;
#pragma unroll
    for (int q = 0; q < 8; q++) ob[q] = fminf(fmaxf(acc[q] + bias, -1.f), 1.f);
}

// ---------------------------------------------------------------------------
// K6: deterministic loss reduction: mean over B*N*C = 4194304 elements
// ---------------------------------------------------------------------------
__global__ __launch_bounds__(256) void k_reduce(const float* __restrict__ partials,
                                                float* __restrict__ loss) {
    __shared__ float red[256];
    const int t = threadIdx.x;
    float s = 0.f;
    for (int i = t; i < 512; i += 256) s += partials[i];
    red[t] = s;
    __syncthreads();
    for (int off = 128; off > 0; off >>= 1) {
        if (t < off) red[t] += red[t + off];
        __syncthreads();
    }
    if (t == 0) loss[0] = red[0] * (1.0f / 4194304.0f);
}

extern "C" void kernel_launch(void* const* d_in, const int* in_sizes, int n_in,
                              void* d_out, int out_size, void* d_ws, size_t ws_size,
                              hipStream_t stream) {
    const float* x  = (const float*)d_in[0];
    const float* w1 = (const float*)d_in[1];
    const float* b1 = (const float*)d_in[2];
    const float* w2 = (const float*)d_in[3];
    const float* b2 = (const float*)d_in[4];
    const float* cb = (const float*)d_in[5];
    const float* w3 = (const float*)d_in[6];
    const float* b3 = (const float*)d_in[7];
    const float* w4 = (const float*)d_in[8];
    const float* b4 = (const float*)d_in[9];

    float* ws = (float*)d_ws;
    float* h1 = ws;                  // 8388608 floats [128,16,64,64]
    float* h  = ws + 8388608;        // 4194304 floats [128,32,32,32]
    float* g  = h1;                  // alias: h1 dead after k_conv2
    float2* part = (float2*)ws;      // alias h1 too: 524288 float2 (4MB) used
                                     // between k_vq_part and k_vq_comb only;
                                     // conv3 overwrites afterwards (in-order stream)
    float* ccp = ws + 12582912;      // 512 floats
    float* pa  = ws + 12583424;      // 512 floats (per-block loss partials)
    float* outp = (float*)d_out;     // [out 2097152][idx 131072][loss 1]

    k_prep<<<2, 256, 0, stream>>>(cb, ccp);
    k_conv1<<<2048, 256, 0, stream>>>(x, w1, b1, h1);
    k_conv2<<<2048, 256, 0, stream>>>(h1, w2, b2, h);
    k_vq_part<<<2048, 256, 0, stream>>>(h, cb, ccp, part);
    k_vq_comb<<<512, 256, 0, stream>>>(part, outp + 2097152, pa);
    k_conv3<<<512, 256, 0, stream>>>(h, w3, b3, g);
    k_conv4<<<1024, 256, 0, stream>>>(g, w4, b4, outp);
    k_reduce<<<1, 256, 0, stream>>>(pa, outp + 2228224);
}

// Round 4
// 238.410 us; speedup vs baseline: 1.8848x; 1.2288x over previous
//
#include <hip/hip_runtime.h>
#include <math.h>

__device__ __forceinline__ float gelu_f(float x) {
    return 0.5f * x * (1.0f + erff(x * 0.7071067811865476f));
}

// ---------------------------------------------------------------------------
// K0: precompute cc[k] = sum_c cb[k][c]^2   (512 codes, 32 ch)
// ---------------------------------------------------------------------------
__global__ __launch_bounds__(256) void k_prep(const float* __restrict__ cb,
                                              float* __restrict__ ccp) {
    const int k = blockIdx.x * 256 + threadIdx.x;
    if (k < 512) {
        const float* row = cb + k * 32;
        float s = 0.f;
#pragma unroll
        for (int c = 0; c < 32; ++c) s += row[c] * row[c];
        ccp[k] = s;
    }
}

// ---------------------------------------------------------------------------
// K1: conv1 (1->16, 3x3, SAME) + maxpool2 + gelu
// x[128,1,128,128] -> h1[128,16,64,64]
// Weights via wave-uniform s_load (no LDS weight traffic). Input pat via
// aligned float2 LDS reads. Accumulation order identical to prior rounds.
// ---------------------------------------------------------------------------
__global__ __launch_bounds__(256) void k_conv1(const float* __restrict__ x,
                                               const float* __restrict__ w1,
                                               const float* __restrict__ b1,
                                               float* __restrict__ h1) {
    __shared__ float xs[34][36];
    const int blk = blockIdx.x;
    const int b = blk >> 4;
    const int tile = blk & 15;
    const int ti = (tile >> 2) << 4, tj = (tile & 3) << 4;
    const int t = threadIdx.x;
    const float* xb = x + b * 16384;
    for (int i = t; i < 34 * 34; i += 256) {
        const int r = i / 34, c = i % 34;
        const int gr = 2 * ti - 1 + r, gc = 2 * tj - 1 + c;
        xs[r][c] = ((unsigned)gr < 128u && (unsigned)gc < 128u) ? xb[gr * 128 + gc] : 0.f;
    }
    __syncthreads();
    const int jj = t & 15, ii = t >> 4;
    float pat[4][4];
#pragma unroll
    for (int r = 0; r < 4; r++) {
        const float2 p0 = *(const float2*)&xs[2 * ii + r][2 * jj];
        const float2 p1 = *(const float2*)&xs[2 * ii + r][2 * jj + 2];
        pat[r][0] = p0.x; pat[r][1] = p0.y; pat[r][2] = p1.x; pat[r][3] = p1.y;
    }
    const int obase = b * 65536 + (ti + ii) * 64 + (tj + jj);
#pragma unroll 2
    for (int co = 0; co < 16; co++) {
        const float* wr = w1 + co * 9;
        float w[9];
#pragma unroll
        for (int k = 0; k < 9; k++) w[k] = wr[k];
        float s00 = 0.f, s01 = 0.f, s10 = 0.f, s11 = 0.f;
#pragma unroll
        for (int ty = 0; ty < 3; ty++)
#pragma unroll
            for (int tx = 0; tx < 3; tx++) {
                const float wv = w[ty * 3 + tx];
                s00 += wv * pat[ty][tx];
                s01 += wv * pat[ty][tx + 1];
                s10 += wv * pat[ty + 1][tx];
                s11 += wv * pat[ty + 1][tx + 1];
            }
        const float m = fmaxf(fmaxf(s00, s01), fmaxf(s10, s11)) + b1[co];
        h1[obase + co * 4096] = gelu_f(m);
    }
}

// ---------------------------------------------------------------------------
// K2: conv2 (16->32, 3x3, SAME) + maxpool2
// h1[128,16,64,64] -> h[128,32,32,32]
// Wave = co-octet (weights wave-uniform -> SGPR). Lane = 8x8 pooled tile pos.
// Per ci: 8 float2 LDS reads feed 288 FMAs (8 co x 36).
// ---------------------------------------------------------------------------
__global__ __launch_bounds__(256) void k_conv2(const float* __restrict__ h1,
                                               const float* __restrict__ w2,
                                               const float* __restrict__ b2,
                                               float* __restrict__ h) {
    __shared__ float hs[16][18][20];
    const int blk = blockIdx.x;
    const int b = blk >> 4;
    const int tile = blk & 15;
    const int ti = (tile >> 2) << 3, tj = (tile & 3) << 3;
    const int t = threadIdx.x;
    const float* h1b = h1 + b * 65536;
    for (int i = t; i < 16 * 324; i += 256) {
        const int ci = i / 324, rc = i % 324, r = rc / 18, c = rc % 18;
        const int gr = 2 * ti - 1 + r, gc = 2 * tj - 1 + c;
        hs[ci][r][c] = ((unsigned)gr < 64u && (unsigned)gc < 64u) ? h1b[ci * 4096 + gr * 64 + gc] : 0.f;
    }
    __syncthreads();
    const int co0 = __builtin_amdgcn_readfirstlane((t >> 6) << 3);
    const int lane = t & 63;
    const int irow = lane >> 3, j = lane & 7;
    float acc[8][4];
#pragma unroll
    for (int q = 0; q < 8; q++) { acc[q][0] = 0.f; acc[q][1] = 0.f; acc[q][2] = 0.f; acc[q][3] = 0.f; }
    const float* wbase = w2 + co0 * 144;
#pragma unroll 4
    for (int ci = 0; ci < 16; ci++) {
        float pat[4][4];
#pragma unroll
        for (int r = 0; r < 4; r++) {
            const float2 p0 = *(const float2*)&hs[ci][2 * irow + r][2 * j];
            const float2 p1 = *(const float2*)&hs[ci][2 * irow + r][2 * j + 2];
            pat[r][0] = p0.x; pat[r][1] = p0.y; pat[r][2] = p1.x; pat[r][3] = p1.y;
        }
#pragma unroll
        for (int q = 0; q < 8; q++) {
            const float* wr = wbase + q * 144 + ci * 9;
            float w[9];
#pragma unroll
            for (int k = 0; k < 9; k++) w[k] = wr[k];
#pragma unroll
            for (int ty = 0; ty < 3; ty++)
#pragma unroll
                for (int tx = 0; tx < 3; tx++) {
                    const float wv = w[ty * 3 + tx];
                    acc[q][0] += wv * pat[ty][tx];
                    acc[q][1] += wv * pat[ty][tx + 1];
                    acc[q][2] += wv * pat[ty + 1][tx];
                    acc[q][3] += wv * pat[ty + 1][tx + 1];
                }
        }
    }
    float* hb = h + (b * 32 + co0) * 1024 + (ti + irow) * 32 + tj + j;
#pragma unroll
    for (int q = 0; q < 8; q++) {
        hb[q * 1024] = fmaxf(fmaxf(acc[q][0], acc[q][1]), fmaxf(acc[q][2], acc[q][3])) + b2[co0 + q];
    }
}

// ---------------------------------------------------------------------------
// K3a: VQ partial argmin (unchanged from passing R3).
// ---------------------------------------------------------------------------
__global__ __launch_bounds__(256) void k_vq_part(const float* __restrict__ h,
                                                 const float* __restrict__ cb,
                                                 const float* __restrict__ ccp,
                                                 float2* __restrict__ part) {
    const int blk = blockIdx.x;
    const int nchunk = blk >> 2, ks = blk & 3;
    const int t = threadIdx.x;
    const int n = nchunk * 256 + t;
    const int b = n >> 10, pos = n & 1023;
    const float* hb = h + b * 32768 + pos;
    float z[32];
    float zz = 0.f;
#pragma unroll
    for (int c = 0; c < 32; ++c) {
        z[c] = hb[c * 1024];
        zz += z[c] * z[c];
    }
    const int kbase = ks << 7;
    const float* cbb = cb + (kbase << 5);
    const float* ccb = ccp + kbase;
    float bd = 3.4e38f;
    int bk = 0;
#pragma unroll 1
    for (int kk = 0; kk < 128; kk += 2) {
        const float* r0 = cbb + (kk << 5);
        const float* r1 = r0 + 32;
        float d0a = 0.f, d0b = 0.f, d1a = 0.f, d1b = 0.f;
#pragma unroll
        for (int c = 0; c < 32; c += 2) {
            d0a += z[c] * r0[c];
            d0b += z[c + 1] * r0[c + 1];
            d1a += z[c] * r1[c];
            d1b += z[c + 1] * r1[c + 1];
        }
        const float dot0 = d0a + d0b;
        const float dot1 = d1a + d1b;
        const float e0 = (zz - 2.f * dot0) + ccb[kk];
        const float e1 = (zz - 2.f * dot1) + ccb[kk + 1];
        if (e0 < bd) { bd = e0; bk = kbase + kk; }
        if (e1 < bd) { bd = e1; bk = kbase + kk + 1; }
    }
    part[ks * 131072 + n] = make_float2(bd, (float)bk);
}

// ---------------------------------------------------------------------------
// K3b: combine 4 k-split partials per n (unchanged).
// ---------------------------------------------------------------------------
__global__ __launch_bounds__(256) void k_vq_comb(const float2* __restrict__ part,
                                                 float* __restrict__ idx_out,
                                                 float* __restrict__ partials) {
    const int t = threadIdx.x;
    const int n = blockIdx.x * 256 + t;
    float2 p0 = part[n];
    float2 p1 = part[131072 + n];
    float2 p2 = part[262144 + n];
    float2 p3 = part[393216 + n];
    float bd = p0.x;
    float bk = p0.y;
    if (p1.x < bd) { bd = p1.x; bk = p1.y; }
    if (p2.x < bd) { bd = p2.x; bk = p2.y; }
    if (p3.x < bd) { bd = p3.x; bk = p3.y; }
    idx_out[n] = bk;
    __shared__ float red[256];
    red[t] = bd;
    __syncthreads();
    for (int off = 128; off > 0; off >>= 1) {
        if (t < off) red[t] += red[t + off];
        __syncthreads();
    }
    if (t == 0) partials[blockIdx.x] = red[0];
}

// ---------------------------------------------------------------------------
// K4: conv3 (32->16, 3x3, SAME) on nearest-2x-upsampled h, + gelu.
// h[128,32,32,32] -> g[128,16,64,64]
// Wave = co-quad (SGPR weights). Lane = out-row-pair (shares 3 h rows) x
// 8-col group. ci staged in 2 chunks of 16 (23KB LDS). Parity weight
// combines identical to R3 formulas.
// ---------------------------------------------------------------------------
__global__ __launch_bounds__(256) void k_conv3(const float* __restrict__ h,
                                               const float* __restrict__ w3,
                                               const float* __restrict__ b3,
                                               float* __restrict__ g) {
    __shared__ float hS[16][10][38];
    const int blk = blockIdx.x;
    const int b = blk >> 2, strip = blk & 3;
    const int i0 = strip * 8;
    const int t = threadIdx.x;
    const int co0 = __builtin_amdgcn_readfirstlane((t >> 6) << 2);
    const int lane = t & 63;
    const int rp = lane >> 3, cg = lane & 7;
    float acc[4][2][8];
#pragma unroll
    for (int cq = 0; cq < 4; cq++)
#pragma unroll
        for (int rr = 0; rr < 2; rr++)
#pragma unroll
            for (int u = 0; u < 8; u++) acc[cq][rr][u] = 0.f;
    const float* hb = h + b * 32768;
#pragma unroll 1
    for (int chunk = 0; chunk < 2; chunk++) {
        __syncthreads();
        for (int i = t; i < 16 * 340; i += 256) {
            const int cil = i / 340, rc = i % 340, r = rc / 34, c = rc % 34;
            const int gr = i0 - 1 + r, gc = c - 1;
            hS[cil][r][c] = ((unsigned)gr < 32u && (unsigned)gc < 32u)
                ? hb[(chunk * 16 + cil) * 1024 + gr * 32 + gc] : 0.f;
        }
        __syncthreads();
#pragma unroll 2
        for (int cil = 0; cil < 16; cil++) {
            const int ci = chunk * 16 + cil;
            float colr[3][6];
#pragma unroll
            for (int rr = 0; rr < 3; rr++) {
                const float2 c0 = *(const float2*)&hS[cil][rp + rr][4 * cg];
                const float2 c1 = *(const float2*)&hS[cil][rp + rr][4 * cg + 2];
                const float2 c2 = *(const float2*)&hS[cil][rp + rr][4 * cg + 4];
                colr[rr][0] = c0.x; colr[rr][1] = c0.y; colr[rr][2] = c1.x;
                colr[rr][3] = c1.y; colr[rr][4] = c2.x; colr[rr][5] = c2.y;
            }
#pragma unroll
            for (int cq = 0; cq < 4; cq++) {
                const float* wr = w3 + ((co0 + cq) * 32 + ci) * 9;
                float w[9];
#pragma unroll
                for (int k = 0; k < 9; k++) w[k] = wr[k];
                // row triples: even out row uses rows (iq-1: T0, iq: T1); odd uses (iq: T2, iq+1: T3)
                const float T00 = w[0], T01 = w[1], T02 = w[2];
                const float T10 = w[3] + w[6], T11 = w[4] + w[7], T12 = w[5] + w[8];
                const float T20 = w[0] + w[3], T21 = w[1] + w[4], T22 = w[2] + w[5];
                const float T30 = w[6], T31 = w[7], T32 = w[8];
                const float E01 = T01 + T02, O00 = T00 + T01;
                const float E11 = T11 + T12, O10 = T10 + T11;
                const float E21 = T21 + T22, O20 = T20 + T21;
                const float E31 = T31 + T32, O30 = T30 + T31;
#pragma unroll
                for (int mm = 0; mm < 4; mm++) {
                    acc[cq][0][2 * mm]     += T00 * colr[0][mm] + E01 * colr[0][mm + 1] + T10 * colr[1][mm] + E11 * colr[1][mm + 1];
                    acc[cq][0][2 * mm + 1] += O00 * colr[0][mm + 1] + T02 * colr[0][mm + 2] + O10 * colr[1][mm + 1] + T12 * colr[1][mm + 2];
                    acc[cq][1][2 * mm]     += T20 * colr[1][mm] + E21 * colr[1][mm + 1] + T30 * colr[2][mm] + E31 * colr[2][mm + 1];
                    acc[cq][1][2 * mm + 1] += O20 * colr[1][mm + 1] + T22 * colr[1][mm + 2] + O30 * colr[2][mm + 1] + T32 * colr[2][mm + 2];
                }
            }
        }
    }
    const int p_e = strip * 16 + 2 * rp;
#pragma unroll
    for (int cq = 0; cq < 4; cq++) {
        const float bias = b3[co0 + cq];
        float* gb = g + (b * 16 + co0 + cq) * 4096 + p_e * 64 + 8 * cg;
#pragma unroll
        for (int rr = 0; rr < 2; rr++) {
            float4 v0, v1;
            v0.x = gelu_f(acc[cq][rr][0] + bias);
            v0.y = gelu_f(acc[cq][rr][1] + bias);
            v0.z = gelu_f(acc[cq][rr][2] + bias);
            v0.w = gelu_f(acc[cq][rr][3] + bias);
            v1.x = gelu_f(acc[cq][rr][4] + bias);
            v1.y = gelu_f(acc[cq][rr][5] + bias);
            v1.z = gelu_f(acc[cq][rr][6] + bias);
            v1.w = gelu_f(acc[cq][rr][7] + bias);
            *(float4*)(gb + rr * 64) = v0;
            *(float4*)(gb + rr * 64 + 4) = v1;
        }
    }
}

// ---------------------------------------------------------------------------
// K5: conv4 (16->1, 3x3, SAME) on nearest-2x-upsampled g, + clip [-1,1].
// g[128,16,64,64] -> out[128,1,128,128]
// Single co: weights fully wave-uniform (SGPR). Lane = out-row-pair x 4-col
// group. ci staged in 2 chunks of 8 (21.8KB LDS).
// ---------------------------------------------------------------------------
__global__ __launch_bounds__(256) void k_conv4(const float* __restrict__ g,
                                               const float* __restrict__ w4,
                                               const float* __restrict__ b4,
                                               float* __restrict__ out) {
    __shared__ float gS[8][10][68];
    const int blk = blockIdx.x;
    const int b = blk >> 3, strip = blk & 7;
    const int i0 = strip * 8;
    const int t = threadIdx.x;
    const int rp = t >> 5, cg = t & 31;
    float acc[2][4];
#pragma unroll
    for (int rr = 0; rr < 2; rr++)
#pragma unroll
        for (int u = 0; u < 4; u++) acc[rr][u] = 0.f;
    const float* gbs = g + b * 65536;
#pragma unroll 1
    for (int chunk = 0; chunk < 2; chunk++) {
        __syncthreads();
        for (int i = t; i < 8 * 660; i += 256) {
            const int cil = i / 660, rc = i % 660, r = rc / 66, c = rc % 66;
            const int gr = i0 - 1 + r, gc = c - 1;
            gS[cil][r][c] = ((unsigned)gr < 64u && (unsigned)gc < 64u)
                ? gbs[(chunk * 8 + cil) * 4096 + gr * 64 + gc] : 0.f;
        }
        __syncthreads();
#pragma unroll 2
        for (int cil = 0; cil < 8; cil++) {
            const int ci = chunk * 8 + cil;
            float colv[3][4];
#pragma unroll
            for (int rr = 0; rr < 3; rr++) {
                const float2 c0 = *(const float2*)&gS[cil][rp + rr][2 * cg];
                const float2 c1 = *(const float2*)&gS[cil][rp + rr][2 * cg + 2];
                colv[rr][0] = c0.x; colv[rr][1] = c0.y; colv[rr][2] = c1.x; colv[rr][3] = c1.y;
            }
            const float* wr = w4 + ci * 9;
            float w[9];
#pragma unroll
            for (int k = 0; k < 9; k++) w[k] = wr[k];
            const float T00 = w[0], T01 = w[1], T02 = w[2];
            const float T10 = w[3] + w[6], T11 = w[4] + w[7], T12 = w[5] + w[8];
            const float T20 = w[0] + w[3], T21 = w[1] + w[4], T22 = w[2] + w[5];
            const float T30 = w[6], T31 = w[7], T32 = w[8];
            const float E01 = T01 + T02, O00 = T00 + T01;
            const float E11 = T11 + T12, O10 = T10 + T11;
            const float E21 = T21 + T22, O20 = T20 + T21;
            const float E31 = T31 + T32, O30 = T30 + T31;
#pragma unroll
            for (int mm = 0; mm < 2; mm++) {
                acc[0][2 * mm]     += T00 * colv[0][mm] + E01 * colv[0][mm + 1] + T10 * colv[1][mm] + E11 * colv[1][mm + 1];
                acc[0][2 * mm + 1] += O00 * colv[0][mm + 1] + T02 * colv[0][mm + 2] + O10 * colv[1][mm + 1] + T12 * colv[1][mm + 2];
                acc[1][2 * mm]     += T20 * colv[1][mm] + E21 * colv[1][mm + 1] + T30 * colv[2][mm] + E31 * colv[2][mm + 1];
                acc[1][2 * mm + 1] += O20 * colv[1][mm + 1] + T22 * colv[1][mm + 2] + O30 * colv[2][mm + 1] + T32 * colv[2][mm + 2];
            }
        }
    }
    const float bias = b4[0];
    const int p_e = strip * 16 + 2 * rp;
    float* ob = out + b * 16384 + p_e * 128 + 4 * cg;
#pragma unroll
    for (int rr = 0; rr < 2; rr++) {
        float4 v;
        v.x = fminf(fmaxf(acc[rr][0] + bias, -1.f), 1.f);
        v.y = fminf(fmaxf(acc[rr][1] + bias, -1.f), 1.f);
        v.z = fminf(fmaxf(acc[rr][2] + bias, -1.f), 1.f);
        v.w = fminf(fmaxf(acc[rr][3] + bias, -1.f), 1.f);
        *(float4*)(ob + rr * 128) = v;
    }
}

// ---------------------------------------------------------------------------
// K6: deterministic loss reduction
// ---------------------------------------------------------------------------
__global__ __launch_bounds__(256) void k_reduce(const float* __restrict__ partials,
                                                float* __restrict__ loss) {
    __shared__ float red[256];
    const int t = threadIdx.x;
    float s = 0.f;
    for (int i = t; i < 512; i += 256) s += partials[i];
    red[t] = s;
    __syncthreads();
    for (int off = 128; off > 0; off >>= 1) {
        if (t < off) red[t] += red[t + off];
        __syncthreads();
    }
    if (t == 0) loss[0] = red[0] * (1.0f / 4194304.0f);
}

extern "C" void kernel_launch(void* const* d_in, const int* in_sizes, int n_in,
                              void* d_out, int out_size, void* d_ws, size_t ws_size,
                              hipStream_t stream) {
    const float* x  = (const float*)d_in[0];
    const float* w1 = (const float*)d_in[1];
    const float* b1 = (const float*)d_in[2];
    const float* w2 = (const float*)d_in[3];
    const float* b2 = (const float*)d_in[4];
    const float* cb = (const float*)d_in[5];
    const float* w3 = (const float*)d_in[6];
    const float* b3 = (const float*)d_in[7];
    const float* w4 = (const float*)d_in[8];
    const float* b4 = (const float*)d_in[9];

    float* ws = (float*)d_ws;
    float* h1 = ws;                  // 8388608 floats [128,16,64,64]
    float* h  = ws + 8388608;        // 4194304 floats [128,32,32,32]
    float* g  = h1;                  // alias: h1 dead after k_conv2
    float2* part = (float2*)ws;      // alias h1: live only vq_part -> vq_comb
    float* ccp = ws + 12582912;      // 512 floats
    float* pa  = ws + 12583424;      // 512 floats
    float* outp = (float*)d_out;     // [out 2097152][idx 131072][loss 1]

    k_prep<<<2, 256, 0, stream>>>(cb, ccp);
    k_conv1<<<2048, 256, 0, stream>>>(x, w1, b1, h1);
    k_conv2<<<2048, 256, 0, stream>>>(h1, w2, b2, h);
    k_vq_part<<<2048, 256, 0, stream>>>(h, cb, ccp, part);
    k_vq_comb<<<512, 256, 0, stream>>>(part, outp + 2097152, pa);
    k_conv3<<<512, 256, 0, stream>>>(h, w3, b3, g);
    k_conv4<<<1024, 256, 0, stream>>>(g, w4, b4, outp);
    k_reduce<<<1, 256, 0, stream>>>(pa, outp + 2228224);
}